// Round 9
// baseline (116.383 us; speedup 1.0000x reference)
//
#include <hip/hip_runtime.h>

#define COUT_  128
#define KP     1024          // K layout: (cin>>1)*32 + k*2 + (cin&1); k>=9 -> pad zeros
#define CAPR   16            // img rows loaded (multiple of 4); +1 zero pad row
#define IMGP   (17 * 64)     // u32 per cin plane (16 rows + pad row) = 1088
#define IMGBUF (2 * IMGP)    // per group buffer (2 planes) = 2176 u32
#define COLW   20            // u32 per px per col row (80 B, 16B-aligned; 2-way banks ok)
#define COLBUF (32 * COLW)   // 640 u32 per buf
#define WS_NEED (size_t)(COUT_ * KP * 2 + 8ull * 64 * 64 * 64 * 4)

#if __has_builtin(__builtin_amdgcn_fdot2_f32_bf16)
#define HAS_DOT2 1
#else
#define HAS_DOT2 0
#endif

typedef __attribute__((ext_vector_type(8))) __bf16 bf16x8;
typedef __attribute__((ext_vector_type(2))) __bf16 bf16x2;
typedef unsigned short u16x8 __attribute__((ext_vector_type(8)));
typedef __attribute__((ext_vector_type(4))) float f32x4;

__device__ __forceinline__ unsigned int f2bf(float f) {
    union { float f; unsigned int u; } c; c.f = f;
    unsigned int u = c.u;
    u += 0x7fffu + ((u >> 16) & 1u);   // RNE
    return u >> 16;
}
__device__ __forceinline__ float bitsf(unsigned int u) {
    union { unsigned int u; float f; } c; c.u = u; return c.f;
}
__device__ __forceinline__ unsigned int pk2bf(float lo, float hi) {
    return f2bf(lo) | (f2bf(hi) << 16);
}
__device__ __forceinline__ bf16x2 mk_bf2(float lo, float hi) {
    unsigned int u = pk2bf(lo, hi);
    return __builtin_bit_cast(bf16x2, u);
}
__device__ __forceinline__ void gl_lds16(const unsigned int* g, unsigned int* l) {
    __builtin_amdgcn_global_load_lds(
        (const __attribute__((address_space(1))) unsigned int*)g,
        (__attribute__((address_space(3))) unsigned int*)l, 16, 0, 0);
}

// merged prep: blocks [0,512) -> weights, [512, 8704) -> paired rgb
__global__ void prep_all(const float* __restrict__ w, unsigned short* __restrict__ wbf,
                         const float* __restrict__ rgb, unsigned int* __restrict__ rgbp,
                         int do_rgb) {
    const int bx = blockIdx.x;
    if (bx < 512) {
        int idx = bx * 256 + threadIdx.x;           // < 131072 = COUT_*KP
        int cout = idx >> 10, r = idx & 1023;
        int pair = r >> 5, j2 = r & 31;
        int k = j2 >> 1, par = j2 & 1;
        unsigned short v = 0;
        if (j2 < 18) v = (unsigned short)f2bf(w[(cout * 64 + pair * 2 + par) * 9 + k]);
        wbf[idx] = v;
    } else if (do_rgb) {
        int idx = (bx - 512) * 256 + threadIdx.x;   // < 2097152
        float a = rgb[idx];
        float nb = ((idx & 63) == 63) ? 0.f : rgb[idx + 1];
        rgbp[idx] = f2bf(a) | (f2bf(nb) << 16);
    }
}

template<bool PREP>
__launch_bounds__(256, 4)
__global__ void deform_mfma9(const float* __restrict__ rgb,
                             const unsigned int* __restrict__ rgbp,
                             const float* __restrict__ off,
                             const unsigned short* __restrict__ wbf,
                             const float* __restrict__ bias,
                             float* __restrict__ out) {
    // [col dbuf: 2x640 u32][img dbuf: 2x2176 u32] = 22528 B -> 4 blocks/CU (grid cap)
    __shared__ unsigned int S[2 * COLBUF + 2 * IMGBUF];
    __shared__ int sYmin, sYmax;
    unsigned int* imgU = S + 2 * COLBUF;

    const int t    = threadIdx.x;
    const int bid  = blockIdx.x;
    const int b    = bid & 7;            // XCD pin
    const int ho   = (bid >> 3) & 63;
    const int px0  = (bid >> 9) * 32;    // half-row
    const int lane = t & 63;
    const int wv   = t >> 6;
    const int px   = t & 31;             // gather pixel
    const int tg   = t >> 5;             // tap group 0..7
    const int ln15 = lane & 15;
    const int q    = lane >> 4;

    const float* offb = off + b * (2 * 9 * 4096);

    // ---- zero ALL of S once: col pad K-slots + img unwritten rows stay 0 (NaN-proof) ----
    {
        uint4* S4 = (uint4*)S;
        const int n4 = (2 * COLBUF + 2 * IMGBUF) / 4;
        for (int i = t; i < n4; i += 256) S4[i] = make_uint4(0, 0, 0, 0);
    }
    if (t == 0) { sYmin = 64; sYmax = -1; }
    __syncthreads();

    // ---- meta A: taps {tg, 8} for pixel px ----
    float m_fy[2], m_fx[2]; int m_y0[2], m_x0[2];
    int lmin = 64, lmax = -1;
#pragma unroll
    for (int ti = 0; ti < 2; ti++) {
        const int kt = ti ? 8 : tg;
        const int wo = px0 + px;
        const float dy = offb[((2 * kt)     * 64 + ho) * 64 + wo];
        const float dx = offb[((2 * kt + 1) * 64 + ho) * 64 + wo];
        const float y = (float)(ho - 1 + kt / 3) + dy;
        const float x = (float)(wo - 1 + kt % 3) + dx;
        const float y0f = floorf(y), x0f = floorf(x);
        m_fy[ti] = y - y0f; m_fx[ti] = x - x0f;
        m_y0[ti] = (int)y0f; m_x0[ti] = (int)x0f;
        const int r0 = min(max(m_y0[ti], 0), 63), r1 = min(max(m_y0[ti] + 1, 0), 63);
        lmin = min(lmin, r0); lmax = max(lmax, r1);
    }
    atomicMin(&sYmin, lmin); atomicMax(&sYmax, lmax);
    __syncthreads();
    const int ymin  = sYmin;
    const int nrows = sYmax - ymin + 1;
    const int nr4   = min((nrows + 3) & ~3, CAPR);
    const int ymin2 = max(0, min(ymin, 64 - nr4));

    // ---- staging: group gg = cin pair {2gg, 2gg+1}; wave wv does chunks {wv, wv+4} ----
    // chunk c: plane = c>>2, rows [(c&3)*4, +4)
    auto stage_dma = [&](int gg) {
#pragma unroll
        for (int u = 0; u < 2; u++) {
            const int c = wv + u * 4;
            const int plane = c >> 2, r4 = (c & 3) * 4;
            if (r4 < nr4) {
                const unsigned int* gp = rgbp
                    + ((unsigned)(b * 64 + gg * 2 + plane) * 64 + ymin2 + r4) * 64 + lane * 4;
                unsigned int* lp = imgU + (gg & 1) * IMGBUF + plane * IMGP + r4 * 64;
                gl_lds16(gp, lp);
            }
        }
    };
    float4 sv[2];
    auto stage_load = [&](int gg) {
#pragma unroll
        for (int u = 0; u < 2; u++) {
            const int c = wv + u * 4;
            const int plane = c >> 2, r4 = (c & 3) * 4;
            if (r4 < nr4)
                sv[u] = *(const float4*)(rgb
                    + ((unsigned)(b * 64 + gg * 2 + plane) * 64 + ymin2 + r4 + (lane >> 4)) * 64
                    + (lane & 15) * 4);
        }
    };
    auto stage_write = [&](int gg) {
#pragma unroll
        for (int u = 0; u < 2; u++) {
            const int c = wv + u * 4;
            const int plane = c >> 2, r4 = (c & 3) * 4;
            const float4 v = sv[u];
            unsigned int b0 = f2bf(v.x), b1 = f2bf(v.y), b2 = f2bf(v.z), b3 = f2bf(v.w);
            unsigned int nb = __shfl(b0, lane + 1);
            if ((lane & 15) == 15) nb = 0;
            if (r4 < nr4) {
                uint4 pk;
                pk.x = b0 | (b1 << 16); pk.y = b1 | (b2 << 16);
                pk.z = b2 | (b3 << 16); pk.w = b3 | (nb << 16);
                *(uint4*)(imgU + (gg & 1) * IMGBUF + plane * IMGP
                          + (r4 + (lane >> 4)) * 64 + (lane & 15) * 4) = pk;
            }
        }
    };

    // ---- meta B: one LDS offset per tap (r1 = r0+1 forced) + packed weights ----
    int ma[2];
#if HAS_DOT2
    bf16x2 wtp[2], wbp[2];
#else
    float mw[2][4];
#endif
#pragma unroll
    for (int ti = 0; ti < 2; ti++) {
        const int y0 = m_y0[ti], x0 = m_x0[ti];
        const float fy = m_fy[ti], fx = m_fx[ti];
        const int r0 = y0 - ymin2;
        const float wy0 = (y0 >= 0  && y0 < 64) ? (1.f - fy) : 0.f;
        const float wy1 = (y0 >= -1 && y0 < 63) ? fy         : 0.f;
        const bool ylo = (r0 < 0);
        const float wtop = ylo ? wy1 : wy0;
        const float wbot = ylo ? 0.f : wy1;
        const int r0c = ylo ? 0 : min(r0, nr4 - 1);   // row r0c+1 <= nr4: zero if unwritten
        const float wx0 = (x0 >= 0  && x0 < 64) ? (1.f - fx) : 0.f;
        const float wx1 = (x0 >= -1 && x0 < 63) ? fx         : 0.f;
        const bool xlo = (x0 < 0);
        const float wA = xlo ? wx1 : wx0;
        const float wB = xlo ? 0.f : wx1;
        const int xc = min(max(x0, 0), 63);
        ma[ti] = r0c * 64 + xc;
#if HAS_DOT2
        wtp[ti] = mk_bf2(wtop * wA, wtop * wB);
        wbp[ti] = mk_bf2(wbot * wA, wbot * wB);
#else
        mw[ti][0] = wtop * wA; mw[ti][1] = wtop * wB;
        mw[ti][2] = wbot * wA; mw[ti][3] = wbot * wB;
#endif
    }

    f32x4 acc[2][2] = {};
    const unsigned short* wrow0 = wbf + (wv * 32 + ln15) * KP;
    const unsigned short* wrow1 = wrow0 + 16 * KP;
    const unsigned short* col16 = (const unsigned short*)S;

    auto interp1 = [&](const unsigned int* pl, int ti) -> float {
        const unsigned int* p = pl + ma[ti];
        const unsigned int tp = p[0];     // rows r0c, r0c+1: const 256B delta -> ds_read2
        const unsigned int bp = p[64];
#if HAS_DOT2
        float r = __builtin_amdgcn_fdot2_f32_bf16(__builtin_bit_cast(bf16x2, tp), wtp[ti], 0.f, false);
        return  __builtin_amdgcn_fdot2_f32_bf16(__builtin_bit_cast(bf16x2, bp), wbp[ti], r, false);
#else
        return mw[ti][0] * bitsf(tp << 16) + mw[ti][1] * bitsf(tp & 0xffff0000u)
             + mw[ti][2] * bitsf(bp << 16) + mw[ti][3] * bitsf(bp & 0xffff0000u);
#endif
    };
    auto gather = [&](int g) {
        const unsigned int* ib = imgU + (g & 1) * IMGBUF;
        unsigned int* cb = S + (g & 1) * COLBUF + px * COLW;
        // tap tg: u32 slot tg = (bf16 plane0, bf16 plane1)
        cb[tg] = pk2bf(interp1(ib, 0), interp1(ib + IMGP, 0));
        // tap 8: rotating owner
        if (tg == (g & 7))
            cb[8] = pk2bf(interp1(ib, 1), interp1(ib + IMGP, 1));
    };
    auto mfma_step = [&](int g, u16x8 a0u, u16x8 a1u) {
        const bf16x8 a0 = __builtin_bit_cast(bf16x8, a0u);
        const bf16x8 a1 = __builtin_bit_cast(bf16x8, a1u);
        const unsigned short* cp = col16 + (g & 1) * (COLBUF * 2) + q * 8;
#pragma unroll
        for (int nj = 0; nj < 2; nj++) {
            const u16x8 bu = *(const u16x8*)(cp + (nj * 16 + ln15) * (COLW * 2));
            const bf16x8 bv = __builtin_bit_cast(bf16x8, bu);
            acc[0][nj] = __builtin_amdgcn_mfma_f32_16x16x32_bf16(a0, bv, acc[0][nj], 0, 0, 0);
            acc[1][nj] = __builtin_amdgcn_mfma_f32_16x16x32_bf16(a1, bv, acc[1][nj], 0, 0, 0);
        }
    };

    if (PREP) stage_dma(0); else { stage_load(0); stage_write(0); }
    __syncthreads();   // img buf 0 ready

    u16x8 pA0 = {}, pA1 = {};
    for (int g = 0; g < 32; g++) {
        if (g + 1 < 32) { if (PREP) stage_dma(g + 1); else stage_load(g + 1); }
        // prefetch A(g) for interval g+1 (latency hidden across the barrier)
        u16x8 nA0 = *(const u16x8*)(wrow0 + g * 32 + q * 8);
        u16x8 nA1 = *(const u16x8*)(wrow1 + g * 32 + q * 8);
        if (g > 0) mfma_step(g - 1, pA0, pA1);
        gather(g);
        if (!PREP && g + 1 < 32) stage_write(g + 1);
        __syncthreads();
        pA0 = nA0; pA1 = nA1;
    }
    mfma_step(31, pA0, pA1);

    // ---- epilogue: C/D map col=lane&15 (px), row=q*4+r (cout) ----
#pragma unroll
    for (int mi = 0; mi < 2; mi++) {
#pragma unroll
        for (int r = 0; r < 4; r++) {
            const int cout = wv * 32 + mi * 16 + q * 4 + r;
            const float bv = bias[cout];
            float* orow = out + ((b * COUT_ + cout) * 64 + ho) * 64 + px0;
#pragma unroll
            for (int nj = 0; nj < 2; nj++)
                orow[nj * 16 + ln15] = acc[mi][nj][r] + bv;
        }
    }
}

extern "C" void kernel_launch(void* const* d_in, const int* in_sizes, int n_in,
                              void* d_out, int out_size, void* d_ws, size_t ws_size,
                              hipStream_t stream) {
    const float* rgb  = (const float*)d_in[0];
    const float* off  = (const float*)d_in[1];
    const float* w    = (const float*)d_in[2];
    const float* bias = (const float*)d_in[3];
    float* out = (float*)d_out;
    unsigned short* wbf = (unsigned short*)d_ws;
    unsigned int* rgbp  = (unsigned int*)((char*)d_ws + COUT_ * KP * 2);

    const int do_rgb = (ws_size >= WS_NEED) ? 1 : 0;
    prep_all<<<do_rgb ? 8704 : 512, 256, 0, stream>>>(w, wbf, rgb, rgbp, do_rgb);
    if (do_rgb)
        deform_mfma9<true><<<1024, 256, 0, stream>>>(rgb, rgbp, off, wbf, bias, out);
    else
        deform_mfma9<false><<<1024, 256, 0, stream>>>(rgb, nullptr, off, wbf, bias, out);
}